// Round 2
// baseline (276.051 us; speedup 1.0000x reference)
//
#include <hip/hip_runtime.h>
#include <stdint.h>

#define BATCH   32
#define ROWS    4096
#define COLS    256
#define COL_IDX 5

typedef unsigned long long u64;
typedef unsigned int       u32;

// ---------------------------------------------------------------------------
// Kernel 1: extract column COL_IDX, pack into order-preserving u64 keys.
//   hi 32 = ~(order_preserving_uint(f))  -> ascending u64 == descending float
//   lo 32 = row index                    -> distinct keys, stable tie-break
// ---------------------------------------------------------------------------
__global__ __launch_bounds__(256)
void extract_keys_kernel(const float* __restrict__ x, u64* __restrict__ keys) {
    const int i = blockIdx.x * 256 + threadIdx.x;      // 0 .. BATCH*ROWS-1
    u32 u = __float_as_uint(x[(size_t)i * COLS + COL_IDX]);
    u = (u >> 31) ? ~u : (u | 0x80000000u);            // order-preserving map
    u = ~u;                                            // descending
    keys[i] = ((u64)u << 32) | (u32)(i & (ROWS - 1));
}

// ---------------------------------------------------------------------------
// Kernel 2: ballot-rank + fused row copy.
// Block owns 64 consecutive rows (lane l <-> row r0+l). Each of the block's
// 4 waves holds its 1024-key quarter in registers (16 x u64 = 32 VGPR) and,
// for each of the block's 64 row-keys m (broadcast via 2 readlanes), counts
// keys < key_m with one v_cmp_lt_u64 (-> sgpr pair via ballot) + s_bcnt1
// per 64-key tile. rank_m is wave-uniform, so it lands in lane m via a
// cndmask select (writelane builtin doesn't exist on this toolchain).
// The wave's 16 output rows are prefetched into 64 VGPRs BEFORE the rank
// loop so the HBM read streams under the VALU work; only the scattered
// 1 KB-row write burst remains after the barrier.
// ---------------------------------------------------------------------------
__global__ __launch_bounds__(256, 4)
void rank_copy_kernel(const float* __restrict__ x,
                      const u64* __restrict__ keys,
                      float* __restrict__ out) {
    __shared__ int part[4][64];
    const int w    = (int)threadIdx.x >> 6;     // wave in block (0..3)
    const int lane = (int)threadIdx.x & 63;
    const int b    = blockIdx.x >> 6;           // 64 blocks per batch
    const int r0   = (blockIdx.x & 63) << 6;    // block's first row
    const u64* __restrict__ kb = keys + (size_t)b * ROWS;

    // ---- prefetch: the 16 rows this wave will copy (64 VGPRs) ----
    const float4* __restrict__ src =
        (const float4*)(x + ((size_t)b * ROWS + r0) * COLS);
    float4 d[16];
    #pragma unroll
    for (int t = 0; t < 16; ++t)
        d[t] = src[(size_t)(w * 16 + t) * 64 + lane];

    // ---- this wave's quarter of the key array (32 VGPRs) ----
    const int jbeg = w * (ROWS / 4);
    u64 kv[16];
    #pragma unroll
    for (int t = 0; t < 16; ++t)
        kv[t] = kb[jbeg + t * 64 + lane];

    const u64 my    = kb[r0 + lane];
    const u32 my_lo = (u32)my, my_hi = (u32)(my >> 32);

    // ---- ballot rank: broadcast row-key m, compare whole quarter ----
    int vrank = 0;
    #pragma unroll 2
    for (int m = 0; m < 64; ++m) {
        const u32 klo = (u32)__builtin_amdgcn_readlane((int)my_lo, m);
        const u32 khi = (u32)__builtin_amdgcn_readlane((int)my_hi, m);
        const u64 mym = ((u64)khi << 32) | klo;
        int rank_m = 0;
        #pragma unroll
        for (int t = 0; t < 16; ++t)
            rank_m += (int)__popcll(__ballot(kv[t] < mym));
        vrank = (lane == m) ? rank_m : vrank;   // uniform rank_m -> lane m
    }

    part[w][lane] = vrank;
    __syncthreads();
    const int total = part[0][lane] + part[1][lane]
                    + part[2][lane] + part[3][lane];

    // ---- scatter the prefetched rows; dst uniform per row -> one 1 KB
    //      contiguous store per row per wave ----
    float4* __restrict__ outb = (float4*)(out + (size_t)b * ROWS * COLS);
    #pragma unroll
    for (int t = 0; t < 16; ++t) {
        const int dst = __builtin_amdgcn_readlane(total, w * 16 + t);
        outb[(size_t)dst * 64 + lane] = d[t];
    }
}

extern "C" void kernel_launch(void* const* d_in, const int* in_sizes, int n_in,
                              void* d_out, int out_size, void* d_ws, size_t ws_size,
                              hipStream_t stream) {
    const float* x   = (const float*)d_in[0];
    float*       out = (float*)d_out;
    u64*         keys = (u64*)d_ws;            // BATCH*ROWS*8 = 1 MB scratch

    extract_keys_kernel<<<(BATCH * ROWS) / 256, 256, 0, stream>>>(x, keys);
    rank_copy_kernel<<<BATCH * 64, 256, 0, stream>>>(x, keys, out);
}

// Round 3
// 243.204 us; speedup vs baseline: 1.1351x; 1.1351x over previous
//
#include <hip/hip_runtime.h>
#include <stdint.h>

#define BATCH   32
#define ROWS    4096
#define COLS    256
#define COL_IDX 5

typedef unsigned long long u64;
typedef unsigned int       u32;

// ---------------------------------------------------------------------------
// Kernel 1: extract column COL_IDX, pack into order-preserving u64 keys.
//   hi 32 = ~(order_preserving_uint(f))  -> ascending u64 == descending float
//   lo 32 = row index                    -> distinct keys, stable tie-break
// ---------------------------------------------------------------------------
__global__ __launch_bounds__(256)
void extract_keys_kernel(const float* __restrict__ x, u64* __restrict__ keys) {
    const int i = blockIdx.x * 256 + threadIdx.x;      // 0 .. BATCH*ROWS-1
    u32 u = __float_as_uint(x[(size_t)i * COLS + COL_IDX]);
    u = (u >> 31) ? ~u : (u | 0x80000000u);            // order-preserving map
    u = ~u;                                            // descending
    keys[i] = ((u64)u << 32) | (u32)(i & (ROWS - 1));
}

// ---------------------------------------------------------------------------
// Kernel 2: ballot-rank + row copy.
// Block owns 64 consecutive rows (lane l <-> row r0+l). Each of the block's
// 4 waves holds its 1024-key quarter in registers (16 x u64 = 32 VGPR) and,
// for each of the block's 64 row-keys m (broadcast via 2 readlanes), counts
// keys < key_m with one v_cmp_lt_u64 (ballot -> sgpr pair) + s_bcnt1 per
// 64-key tile: ~20 VALU + 32 SALU per 1024 compares, SALU riding the
// parallel scalar pipe. rank_m is wave-uniform -> lands in lane m via
// cndmask select.
// R2 LESSON: do NOT prefetch the 16 output rows into registers — under the
// 128-VGPR cap the compiler spills them to scratch, doubling HBM writes
// (WRITE_SIZE 131072 -> 262144 KB). Copy streams straight from L2/HBM
// after the barrier instead; ~55 VGPR total, spill-free.
// ---------------------------------------------------------------------------
__global__ __launch_bounds__(256, 4)
void rank_copy_kernel(const float* __restrict__ x,
                      const u64* __restrict__ keys,
                      float* __restrict__ out) {
    __shared__ int part[4][64];
    const int w    = (int)threadIdx.x >> 6;     // wave in block (0..3)
    const int lane = (int)threadIdx.x & 63;
    const int b    = blockIdx.x >> 6;           // 64 blocks per batch
    const int r0   = (blockIdx.x & 63) << 6;    // block's first row
    const u64* __restrict__ kb = keys + (size_t)b * ROWS;

    // ---- this wave's quarter of the key array (32 VGPRs) ----
    const int jbeg = w * (ROWS / 4);
    u64 kv[16];
    #pragma unroll
    for (int t = 0; t < 16; ++t)
        kv[t] = kb[jbeg + t * 64 + lane];

    const u64 my    = kb[r0 + lane];
    const u32 my_lo = (u32)my, my_hi = (u32)(my >> 32);

    // ---- ballot rank: broadcast row-key m, compare whole quarter ----
    int vrank = 0;
    #pragma unroll 2
    for (int m = 0; m < 64; ++m) {
        const u32 klo = (u32)__builtin_amdgcn_readlane((int)my_lo, m);
        const u32 khi = (u32)__builtin_amdgcn_readlane((int)my_hi, m);
        const u64 mym = ((u64)khi << 32) | klo;
        int rank_m = 0;
        #pragma unroll
        for (int t = 0; t < 16; ++t)
            rank_m += (int)__popcll(__ballot(kv[t] < mym));
        vrank = (lane == m) ? rank_m : vrank;   // uniform rank_m -> lane m
    }

    part[w][lane] = vrank;
    __syncthreads();
    const int total = part[0][lane] + part[1][lane]
                    + part[2][lane] + part[3][lane];

    // ---- copy 64 rows; wave w handles rows [w*16, w*16+16).
    //      1 KB contiguous read + 1 KB contiguous write per row. ----
    const float4* __restrict__ src  =
        (const float4*)(x + ((size_t)b * ROWS + r0) * COLS);
    float4* __restrict__ outb = (float4*)(out + (size_t)b * ROWS * COLS);
    #pragma unroll 4
    for (int t = 0; t < 16; ++t) {
        const int l   = w * 16 + t;
        const int dst = __builtin_amdgcn_readlane(total, l);   // uniform
        outb[(size_t)dst * 64 + lane] = src[(size_t)l * 64 + lane];
    }
}

extern "C" void kernel_launch(void* const* d_in, const int* in_sizes, int n_in,
                              void* d_out, int out_size, void* d_ws, size_t ws_size,
                              hipStream_t stream) {
    const float* x   = (const float*)d_in[0];
    float*       out = (float*)d_out;
    u64*         keys = (u64*)d_ws;            // BATCH*ROWS*8 = 1 MB scratch

    extract_keys_kernel<<<(BATCH * ROWS) / 256, 256, 0, stream>>>(x, keys);
    rank_copy_kernel<<<BATCH * 64, 256, 0, stream>>>(x, keys, out);
}